// Round 4
// baseline (663.857 us; speedup 1.0000x reference)
//
#include <hip/hip_runtime.h>

// DiagLinear: out[t][o*16+p] = sum_i x[t][p*256+i] * W[p][o][i] + bias[o*16+p]
// t in [0,16384), o in [0,256), p in [0,16), i in [0,256)
//
// R6: occupancy fix, carried out inside R4's VERIFIED sync skeleton (explicit
// counted s_waitcnt vmcnt + raw s_barrier; sched_barrier-fenced phases) --
// R5's only unverified leap was trusting __syncthreads to drain LDS-DMA, and
// it produced NaN. Changes vs R4 are decomposition-only:
//   - 1 strip/wave (res[16] = 64 AGPR, single b[8]) instead of 2 -> ~155
//     total regs -> 3 waves/SIMD under __launch_bounds__(256,3)
//   - 256-thread blocks; 4 sibling blocks per token group (strip = sb*4+wv);
//     bijective XCD-chunk swizzle w=(d&7)*512+(d>>3) places the 4 siblings
//     on one XCD so their shared x-slices re-read from L2, not HBM
//   - NBUF=3 slice buffers (49.9 KB LDS) -> LDS admits 3 blocks/CU
//   - wave DMAs 4 token rows/slice (4 ops); waits re-derived: prologue
//     vmcnt(4); steady-state tail vmcnt(4); p==14 tail vmcnt(0).
//     Slice p is drained by iter p-1's b-load wait (same guarantee chain
//     as R4, re-derived for 4 ops/slice, depth-2).
// Fragment/epilogue index math identical to verified R2/R4.

typedef __attribute__((ext_vector_type(4))) float f32x4;
typedef __attribute__((ext_vector_type(8))) short short8;

#define SLICE_STRIDE 1040                  // 256 fp32 + 16B pad
#define BUF_BYTES    (16 * SLICE_STRIDE)   // 16640 B per slice
#define NBUF         3
#define LDS_TOTAL    (NBUF * BUF_BYTES)    // 49920 B -> 3 blocks/CU by LDS

// round-to-nearest-even fp32 -> bf16, packed pair (weight-convert kernel)
__device__ __forceinline__ unsigned int pk2(float a, float b) {
  union { float f; unsigned int u; } x, y;
  x.f = a; y.f = b;
  unsigned int ua = x.u + (0x7fffu + ((x.u >> 16) & 1u));
  unsigned int ub = y.u + (0x7fffu + ((y.u >> 16) & 1u));
  return (ua >> 16) | (ub & 0xffff0000u);
}

// hardware packed cvt (RNE -> bit-identical to pk2)
__device__ __forceinline__ unsigned int cvtpk(float a, float b) {
  unsigned int r;
  asm("v_cvt_pk_bf16_f32 %0, %1, %2" : "=v"(r) : "v"(a), "v"(b));
  return r;
}

__device__ __forceinline__ void dma_row(const float* g, char* l) {
  // wave-uniform LDS base; HW adds lane*16. 64 lanes x 16B = 1KB = one slice row.
  __builtin_amdgcn_global_load_lds(
      (const __attribute__((address_space(1))) unsigned int*)g,
      (__attribute__((address_space(3))) unsigned int*)l, 16, 0, 0);
}

__global__ __launch_bounds__(256) void wconv_kernel(
    const float* __restrict__ w, unsigned int* __restrict__ o) {
  int i = blockIdx.x * 256 + threadIdx.x;
  float4 f = ((const float4*)w)[i];
  uint2 u;
  u.x = pk2(f.x, f.y);
  u.y = pk2(f.z, f.w);
  ((uint2*)o)[i] = u;
}

__global__ __launch_bounds__(256, 3) void diag_gemm_kernel(
    const float* __restrict__ x, const unsigned short* __restrict__ wb,
    const float* __restrict__ bias, float* __restrict__ out) {
  extern __shared__ char lds[];
  const int tid = threadIdx.x;
  const int wv  = tid >> 6;        // wave 0..3
  const int l   = tid & 63;

  // ---- XCD-chunk swizzle: 4 sibling blocks of a token group -> same XCD ----
  const int d = blockIdx.x;                 // grid = 4096, 4096 % 8 == 0
  const int w = (d & 7) * 512 + (d >> 3);   // bijective
  const int g  = w >> 2;                    // token group 0..1023
  const int sb = w & 3;                     // sibling 0..3
  const long T0 = (long)g * 16;

  const int n  = l & 15;           // MFMA col (o_local) / A token row
  const int kg = l >> 4;           // k-group

  const int strip = sb * 4 + wv;   // 0..15 -> o0 = strip*16
  const unsigned short* bbase = wb + (strip * 16 + n) * 256 + kg * 8;
  const float* xdma = x + (T0 + wv * 4) * 4096 + l * 4;   // wave stages 4 rows

  short8 a[8], b[8];
  f32x4 res[16];

  // ---- prologue: DMA slices 0,1 into bufs 0,1 (8 ops) ----
#pragma unroll
  for (int sl = 0; sl < 2; ++sl) {
#pragma unroll
    for (int i = 0; i < 4; ++i)
      dma_row(xdma + i * 4096 + sl * 256,
              lds + sl * BUF_BYTES + (wv * 4 + i) * SLICE_STRIDE);
  }
  __builtin_amdgcn_sched_barrier(0);
  asm volatile("s_waitcnt vmcnt(4)" ::: "memory");  // slice 0 retired; slice 1 in flight
  __builtin_amdgcn_s_barrier();
  __builtin_amdgcn_sched_barrier(0);

#pragma unroll
  for (int p = 0; p < 16; ++p) {
    // ---- b loads FIRST (their wait drains all older DMAs, R4 mechanism) ----
    const unsigned short* bp = bbase + p * 65536;
#pragma unroll
    for (int ks = 0; ks < 8; ++ks) b[ks] = *(const short8*)(bp + ks * 32);
    __builtin_amdgcn_sched_barrier(0);

    // ---- A fragments: fp32 slice p -> bf16 regs ----
    const char* ab = lds + (p % 3) * BUF_BYTES + n * SLICE_STRIDE + kg * 32;
#pragma unroll
    for (int ks = 0; ks < 8; ++ks) {
      f32x4 lo = *(const f32x4*)(ab + ks * 128);
      f32x4 hi = *(const f32x4*)(ab + ks * 128 + 16);
      union { unsigned int u[4]; short8 s8; } t;
      t.u[0] = cvtpk(lo[0], lo[1]);
      t.u[1] = cvtpk(lo[2], lo[3]);
      t.u[2] = cvtpk(hi[0], hi[1]);
      t.u[3] = cvtpk(hi[2], hi[3]);
      a[ks] = t.s8;
    }
    __builtin_amdgcn_sched_barrier(0);

    // ---- async-DMA slice p+2 into buf[(p+2)%3] (newest vmem ops) ----
    if (p < 14) {
#pragma unroll
      for (int i = 0; i < 4; ++i)
        dma_row(xdma + i * 4096 + (p + 2) * 256,
                lds + ((p + 2) % 3) * BUF_BYTES + (wv * 4 + i) * SLICE_STRIDE);
    }
    __builtin_amdgcn_sched_barrier(0);

    // ---- 8 MFMAs ----
    f32x4 acc = (f32x4){0.f, 0.f, 0.f, 0.f};
#pragma unroll
    for (int ks = 0; ks < 8; ++ks)
      acc = __builtin_amdgcn_mfma_f32_16x16x32_bf16(a[ks], b[ks], acc, 0, 0, 0);
    res[p] = acc;

    // ---- tail: counted vmcnt (slice p+2 stays in flight) + raw barrier ----
    if (p < 15) {
      __builtin_amdgcn_sched_barrier(0);
      if (p < 14) asm volatile("s_waitcnt vmcnt(4)" ::: "memory");
      else        asm volatile("s_waitcnt vmcnt(0)" ::: "memory");
      __builtin_amdgcn_s_barrier();
      __builtin_amdgcn_sched_barrier(0);
    }
  }

  // ---- epilogue: lane owns 64B contiguous per row -> full sectors ----
  const int o0 = strip * 16;
  float* obase = out + T0 * 4096;
  const float* bp2 = bias + (o0 + n) * 16;
  float4 bv0 = ((const float4*)bp2)[0];
  float4 bv1 = ((const float4*)bp2)[1];
  float4 bv2 = ((const float4*)bp2)[2];
  float4 bv3 = ((const float4*)bp2)[3];
  float* ob = obase + (long)(o0 + n) * 16;
#pragma unroll
  for (int r = 0; r < 4; ++r) {
    float* orow = ob + (long)(kg * 4 + r) * 4096;
    float4 v0 = make_float4(res[0][r] + bv0.x, res[1][r] + bv0.y,
                            res[2][r] + bv0.z, res[3][r] + bv0.w);
    float4 v1 = make_float4(res[4][r] + bv1.x, res[5][r] + bv1.y,
                            res[6][r] + bv1.z, res[7][r] + bv1.w);
    float4 v2 = make_float4(res[8][r] + bv2.x, res[9][r] + bv2.y,
                            res[10][r] + bv2.z, res[11][r] + bv2.w);
    float4 v3 = make_float4(res[12][r] + bv3.x, res[13][r] + bv3.y,
                            res[14][r] + bv3.z, res[15][r] + bv3.w);
    ((float4*)orow)[0] = v0;
    ((float4*)orow)[1] = v1;
    ((float4*)orow)[2] = v2;
    ((float4*)orow)[3] = v3;
  }
}

extern "C" void kernel_launch(void* const* d_in, const int* in_sizes, int n_in,
                              void* d_out, int out_size, void* d_ws, size_t ws_size,
                              hipStream_t stream) {
  const float* x    = (const float*)d_in[0];   // (8,2048,4096) fp32
  const float* w    = (const float*)d_in[1];   // (16,256,256) fp32
  const float* bias = (const float*)d_in[2];   // (4096,) fp32
  float* out = (float*)d_out;
  unsigned int* wb = (unsigned int*)d_ws;      // 2 MB bf16 weights

  (void)hipFuncSetAttribute((const void*)diag_gemm_kernel,
                            hipFuncAttributeMaxDynamicSharedMemorySize, LDS_TOTAL);

  wconv_kernel<<<1024, 256, 0, stream>>>(w, wb);

  diag_gemm_kernel<<<4096, 256, LDS_TOTAL, stream>>>(
      x, (const unsigned short*)wb, bias, out);
}